// Round 1
// baseline (948.777 us; speedup 1.0000x reference)
//
#include <hip/hip_runtime.h>

#define NN 50000
#define EE 200000
#define RR 4
#define D_IN 128
#define D_H 128
#define D_OUT 64

// ---------------------------------------------------------------------------
// degree count per (etype, dst)
__global__ __launch_bounds__(256) void deg_count_kernel(
    const int* __restrict__ edges, float* __restrict__ deg)
{
    int idx = blockIdx.x * 256 + threadIdx.x;
    if (idx >= RR * EE) return;
    int r = idx / EE;
    int e = idx - r * EE;
    int dst = edges[r * 2 * EE + EE + e];
    atomicAdd(&deg[r * NN + dst], 1.0f);
}

// deg -> 1/max(deg,1) in place
__global__ __launch_bounds__(256) void deg_inv_kernel(float* __restrict__ deg)
{
    int idx = blockIdx.x * 256 + threadIdx.x;
    if (idx >= RR * NN) return;
    deg[idx] = 1.0f / fmaxf(deg[idx], 1.0f);
}

// ---------------------------------------------------------------------------
// C[n x LDM] = (relu?)A[n x 128] @ W[128 x LDM] + b, computed in 64x64 tiles.
// blockIdx.x = row tile (64 rows), blockIdx.y = col tile (64 cols).
// 256 threads: 16 col-threads x 16 row-threads, each does a 4x4 register tile.
// LDS: W sub-block 32KB + A tile 32KB = 64KB -> 2 blocks/CU.
template<int LDM, bool RELU_IN>
__global__ __launch_bounds__(256) void gemm_bias_kernel(
    const float* __restrict__ A, const float* __restrict__ W,
    const float* __restrict__ b, float* __restrict__ C, int n)
{
    __shared__ float Wlds[D_IN * 64];   // [k][j] j = col within tile
    __shared__ float Alds[64 * D_IN];   // [r][k]
    const int tid  = threadIdx.x;
    const int c0   = blockIdx.y * 64;
    const int row0 = blockIdx.x * 64;

    // stage W sub-block [128 x 64], float4 per thread-chunk
    for (int i = tid * 4; i < D_IN * 64; i += 1024) {
        int k = i >> 6;
        int j = i & 63;
        *(float4*)&Wlds[i] = *(const float4*)&W[k * LDM + c0 + j];
    }
    // stage A tile [64 x 128]
    for (int i = tid * 4; i < 64 * D_IN; i += 1024) {
        int rr = i >> 7;
        int kk = i & 127;
        int grow = row0 + rr;
        float4 v = make_float4(0.f, 0.f, 0.f, 0.f);
        if (grow < n) v = *(const float4*)&A[grow * D_IN + kk];
        if (RELU_IN) {
            v.x = fmaxf(v.x, 0.f); v.y = fmaxf(v.y, 0.f);
            v.z = fmaxf(v.z, 0.f); v.w = fmaxf(v.w, 0.f);
        }
        *(float4*)&Alds[i] = v;
    }
    __syncthreads();

    const int cx  = tid & 15;    // col-thread
    const int ry  = tid >> 4;    // row-thread
    const int col = cx * 4;
    const int ar0 = ry * 4;

    float acc[4][4];
    const float4 bv = *(const float4*)&b[c0 + col];
    #pragma unroll
    for (int r = 0; r < 4; ++r) {
        acc[r][0] = bv.x; acc[r][1] = bv.y; acc[r][2] = bv.z; acc[r][3] = bv.w;
    }

    #pragma unroll 2
    for (int k = 0; k < D_IN; k += 4) {
        float4 av[4], wv[4];
        #pragma unroll
        for (int r = 0; r < 4; ++r)
            av[r] = *(const float4*)&Alds[(ar0 + r) * D_IN + k];
        #pragma unroll
        for (int kk = 0; kk < 4; ++kk)
            wv[kk] = *(const float4*)&Wlds[(k + kk) * 64 + col];
        #pragma unroll
        for (int r = 0; r < 4; ++r) {
            acc[r][0] += av[r].x * wv[0].x + av[r].y * wv[1].x + av[r].z * wv[2].x + av[r].w * wv[3].x;
            acc[r][1] += av[r].x * wv[0].y + av[r].y * wv[1].y + av[r].z * wv[2].y + av[r].w * wv[3].y;
            acc[r][2] += av[r].x * wv[0].z + av[r].y * wv[1].z + av[r].z * wv[2].z + av[r].w * wv[3].z;
            acc[r][3] += av[r].x * wv[0].w + av[r].y * wv[1].w + av[r].z * wv[2].w + av[r].w * wv[3].w;
        }
    }

    #pragma unroll
    for (int r = 0; r < 4; ++r) {
        int grow = row0 + ar0 + r;
        if (grow < n) {
            float4 o;
            o.x = acc[r][0]; o.y = acc[r][1]; o.z = acc[r][2]; o.w = acc[r][3];
            *(float4*)&C[grow * LDM + c0 + col] = o;
        }
    }
}

// ---------------------------------------------------------------------------
// out[dst*M + lane] += Wh[src*M + lane] * deg_inv[dst]   (mean + cross-etype sum)
template<int M>
__global__ __launch_bounds__(256) void scatter_kernel(
    const float* __restrict__ Wh, const int* __restrict__ er,
    const float* __restrict__ dinv, float* __restrict__ out)
{
    constexpr int EPB = 256 / M;
    int e = blockIdx.x * EPB + threadIdx.x / M;
    if (e >= EE) return;
    int lane = threadIdx.x & (M - 1);
    int src = er[e];
    int dst = er[EE + e];
    float w = dinv[dst];
    atomicAdd(&out[dst * M + lane], Wh[src * M + lane] * w);
}

// ---------------------------------------------------------------------------
extern "C" void kernel_launch(void* const* d_in, const int* in_sizes, int n_in,
                              void* d_out, int out_size, void* d_ws, size_t ws_size,
                              hipStream_t stream)
{
    const float* feat  = (const float*)d_in[0];   // [N,128]
    const float* W1    = (const float*)d_in[1];   // [R,128,128]
    const float* b1    = (const float*)d_in[2];   // [R,128]
    const float* W2    = (const float*)d_in[3];   // [R,128,64]
    const float* b2    = (const float*)d_in[4];   // [R,64]
    const int*   edges = (const int*)d_in[5];     // [R,2,E]
    float* out = (float*)d_out;                   // [N,64]

    float* deg = (float*)d_ws;                    // R*N
    float* h1  = deg + (size_t)RR * NN;           // N*128 (layer-1 aggregate)
    float* wh  = h1 + (size_t)NN * D_H;           // N*128 scratch (per-etype Wh)

    hipMemsetAsync(deg, 0, (size_t)RR * NN * sizeof(float), stream);
    hipMemsetAsync(h1, 0, (size_t)NN * D_H * sizeof(float), stream);
    hipMemsetAsync(d_out, 0, (size_t)NN * D_OUT * sizeof(float), stream);

    deg_count_kernel<<<(RR * EE + 255) / 256, 256, 0, stream>>>(edges, deg);
    deg_inv_kernel<<<(RR * NN + 255) / 256, 256, 0, stream>>>(deg);

    // ---- layer 1: h1 = sum_r mean_r( feat @ W1[r] + b1[r] ) ----
    for (int r = 0; r < RR; ++r) {
        dim3 g1((NN + 63) / 64, D_H / 64);
        gemm_bias_kernel<D_H, false><<<g1, 256, 0, stream>>>(
            feat, W1 + (size_t)r * D_IN * D_H, b1 + (size_t)r * D_H, wh, NN);
        scatter_kernel<D_H><<<(EE + 1) / 2, 256, 0, stream>>>(
            wh, edges + (size_t)r * 2 * EE, deg + (size_t)r * NN, h1);
    }

    // ---- layer 2: out = sum_r mean_r( relu(h1) @ W2[r] + b2[r] ) ----
    for (int r = 0; r < RR; ++r) {
        dim3 g2((NN + 63) / 64, D_OUT / 64);
        gemm_bias_kernel<D_OUT, true><<<g2, 256, 0, stream>>>(
            h1, W2 + (size_t)r * D_H * D_OUT, b2 + (size_t)r * D_OUT, wh, NN);
        scatter_kernel<D_OUT><<<(EE + 3) / 4, 256, 0, stream>>>(
            wh, edges + (size_t)r * 2 * EE, deg + (size_t)r * NN, out);
    }
}

// Round 2
// 657.339 us; speedup vs baseline: 1.4434x; 1.4434x over previous
//
#include <hip/hip_runtime.h>

#define NN 50000
#define EE 200000
#define RR 4
#define D_IN 128
#define D_H 128
#define D_OUT 64

// ---------------------------------------------------------------------------
// CSR build: histogram of dst per etype
__global__ __launch_bounds__(256) void hist_kernel(
    const int* __restrict__ edges, int* __restrict__ counts)
{
    int idx = blockIdx.x * 256 + threadIdx.x;
    if (idx >= RR * EE) return;
    int r = idx / EE;
    int e = idx - r * EE;
    int dst = edges[r * 2 * EE + EE + e];
    atomicAdd(&counts[r * NN + dst], 1);
}

// per-etype exclusive scan over N counts (one 1024-thread block per etype)
__global__ __launch_bounds__(1024) void scan_kernel(
    const int* __restrict__ counts, int* __restrict__ offsets)
{
    __shared__ int lsum[1024];
    const int r = blockIdx.x;
    const int* c = counts + (size_t)r * NN;
    int* o = offsets + (size_t)r * NN;
    const int t = threadIdx.x;
    const int CH = (NN + 1023) / 1024;   // 49
    int begin = t * CH;
    int end = begin + CH; if (end > NN) end = NN;
    int s = 0;
    for (int i = begin; i < end; ++i) s += c[i];
    lsum[t] = s;
    __syncthreads();
    // Hillis-Steele inclusive scan
    for (int off = 1; off < 1024; off <<= 1) {
        int v = (t >= off) ? lsum[t - off] : 0;
        __syncthreads();
        lsum[t] += v;
        __syncthreads();
    }
    int base = (t > 0) ? lsum[t - 1] : 0;
    for (int i = begin; i < end; ++i) { o[i] = base; base += c[i]; }
}

// scatter src indices into dst-sorted order
__global__ __launch_bounds__(256) void fill_kernel(
    const int* __restrict__ edges, const int* __restrict__ offsets,
    int* __restrict__ cursor, int* __restrict__ ssrc)
{
    int idx = blockIdx.x * 256 + threadIdx.x;
    if (idx >= RR * EE) return;
    int r = idx / EE;
    int e = idx - r * EE;
    int src = edges[r * 2 * EE + e];
    int dst = edges[r * 2 * EE + EE + e];
    int p = offsets[r * NN + dst] + atomicAdd(&cursor[r * NN + dst], 1);
    ssrc[r * EE + p] = src;
}

// ---------------------------------------------------------------------------
// C[n x LDM] = (relu?)A[n x 128] @ W[128 x LDM] + b, 64x64 tiles, fp32 VALU.
template<int LDM, bool RELU_IN>
__global__ __launch_bounds__(256) void gemm_bias_kernel(
    const float* __restrict__ A, const float* __restrict__ W,
    const float* __restrict__ b, float* __restrict__ C, int n)
{
    __shared__ float Wlds[D_IN * 64];   // [k][j]
    __shared__ float Alds[64 * D_IN];   // [r][k]
    const int tid  = threadIdx.x;
    const int c0   = blockIdx.y * 64;
    const int row0 = blockIdx.x * 64;

    for (int i = tid * 4; i < D_IN * 64; i += 1024) {
        int k = i >> 6;
        int j = i & 63;
        *(float4*)&Wlds[i] = *(const float4*)&W[k * LDM + c0 + j];
    }
    for (int i = tid * 4; i < 64 * D_IN; i += 1024) {
        int rr = i >> 7;
        int kk = i & 127;
        int grow = row0 + rr;
        float4 v = make_float4(0.f, 0.f, 0.f, 0.f);
        if (grow < n) v = *(const float4*)&A[grow * D_IN + kk];
        if (RELU_IN) {
            v.x = fmaxf(v.x, 0.f); v.y = fmaxf(v.y, 0.f);
            v.z = fmaxf(v.z, 0.f); v.w = fmaxf(v.w, 0.f);
        }
        *(float4*)&Alds[i] = v;
    }
    __syncthreads();

    const int cx  = tid & 15;
    const int ry  = tid >> 4;
    const int col = cx * 4;
    const int ar0 = ry * 4;

    float acc[4][4];
    const float4 bv = *(const float4*)&b[c0 + col];
    #pragma unroll
    for (int r = 0; r < 4; ++r) {
        acc[r][0] = bv.x; acc[r][1] = bv.y; acc[r][2] = bv.z; acc[r][3] = bv.w;
    }

    #pragma unroll 2
    for (int k = 0; k < D_IN; k += 4) {
        float4 av[4], wv[4];
        #pragma unroll
        for (int r = 0; r < 4; ++r)
            av[r] = *(const float4*)&Alds[(ar0 + r) * D_IN + k];
        #pragma unroll
        for (int kk = 0; kk < 4; ++kk)
            wv[kk] = *(const float4*)&Wlds[(k + kk) * 64 + col];
        #pragma unroll
        for (int r = 0; r < 4; ++r) {
            acc[r][0] += av[r].x * wv[0].x + av[r].y * wv[1].x + av[r].z * wv[2].x + av[r].w * wv[3].x;
            acc[r][1] += av[r].x * wv[0].y + av[r].y * wv[1].y + av[r].z * wv[2].y + av[r].w * wv[3].y;
            acc[r][2] += av[r].x * wv[0].z + av[r].y * wv[1].z + av[r].z * wv[2].z + av[r].w * wv[3].z;
            acc[r][3] += av[r].x * wv[0].w + av[r].y * wv[1].w + av[r].z * wv[2].w + av[r].w * wv[3].w;
        }
    }

    #pragma unroll
    for (int r = 0; r < 4; ++r) {
        int grow = row0 + ar0 + r;
        if (grow < n) {
            float4 o;
            o.x = acc[r][0]; o.y = acc[r][1]; o.z = acc[r][2]; o.w = acc[r][3];
            *(float4*)&C[grow * LDM + c0 + col] = o;
        }
    }
}

// ---------------------------------------------------------------------------
// CSR gather-mean, 128 wide: one 64-lane wave per node, float2 per lane.
template<bool FIRST>
__global__ __launch_bounds__(256) void gather128_kernel(
    const float* __restrict__ wh, const int* __restrict__ ssrc,
    const int* __restrict__ offsets, const int* __restrict__ counts,
    float* __restrict__ acc_out)
{
    int node = blockIdx.x * 4 + (threadIdx.x >> 6);
    if (node >= NN) return;
    int lane = threadIdx.x & 63;
    int start = offsets[node];
    int d = counts[node];
    const int* sp = ssrc + start;
    float2 a = make_float2(0.f, 0.f);
    int j = 0;
    for (; j + 1 < d; j += 2) {
        int s0 = sp[j], s1 = sp[j + 1];
        float2 v0 = *(const float2*)&wh[(size_t)s0 * D_H + lane * 2];
        float2 v1 = *(const float2*)&wh[(size_t)s1 * D_H + lane * 2];
        a.x += v0.x + v1.x; a.y += v0.y + v1.y;
    }
    if (j < d) {
        int s0 = sp[j];
        float2 v0 = *(const float2*)&wh[(size_t)s0 * D_H + lane * 2];
        a.x += v0.x; a.y += v0.y;
    }
    float inv = 1.0f / fmaxf((float)d, 1.0f);
    a.x *= inv; a.y *= inv;
    float2* p = (float2*)&acc_out[(size_t)node * D_H + lane * 2];
    if (FIRST) { *p = a; }
    else { float2 c = *p; c.x += a.x; c.y += a.y; *p = c; }
}

// CSR gather-mean, 64 wide: one 64-lane wave per node, 1 float per lane.
template<bool FIRST>
__global__ __launch_bounds__(256) void gather64_kernel(
    const float* __restrict__ wh, const int* __restrict__ ssrc,
    const int* __restrict__ offsets, const int* __restrict__ counts,
    float* __restrict__ acc_out)
{
    int node = blockIdx.x * 4 + (threadIdx.x >> 6);
    if (node >= NN) return;
    int lane = threadIdx.x & 63;
    int start = offsets[node];
    int d = counts[node];
    const int* sp = ssrc + start;
    float a = 0.f;
    int j = 0;
    for (; j + 1 < d; j += 2) {
        int s0 = sp[j], s1 = sp[j + 1];
        a += wh[(size_t)s0 * D_OUT + lane] + wh[(size_t)s1 * D_OUT + lane];
    }
    if (j < d) a += wh[(size_t)sp[j] * D_OUT + lane];
    a *= 1.0f / fmaxf((float)d, 1.0f);
    float* p = &acc_out[(size_t)node * D_OUT + lane];
    if (FIRST) { *p = a; }
    else { *p += a; }
}

// ---------------------------------------------------------------------------
extern "C" void kernel_launch(void* const* d_in, const int* in_sizes, int n_in,
                              void* d_out, int out_size, void* d_ws, size_t ws_size,
                              hipStream_t stream)
{
    const float* feat  = (const float*)d_in[0];   // [N,128]
    const float* W1    = (const float*)d_in[1];   // [R,128,128]
    const float* b1    = (const float*)d_in[2];   // [R,128]
    const float* W2    = (const float*)d_in[3];   // [R,128,64]
    const float* b2    = (const float*)d_in[4];   // [R,64]
    const int*   edges = (const int*)d_in[5];     // [R,2,E]
    float* out = (float*)d_out;                   // [N,64]

    // workspace layout
    int* counts  = (int*)d_ws;                        // R*N
    int* offsets = counts + (size_t)RR * NN;          // R*N
    int* cursor  = offsets + (size_t)RR * NN;         // R*N
    int* ssrc    = cursor + (size_t)RR * NN;          // R*E
    float* wh    = (float*)(ssrc + (size_t)RR * EE);  // N*128 (per-etype Wh)
    float* h1    = wh + (size_t)NN * D_H;             // N*128 (layer-1 aggregate)

    hipMemsetAsync(counts, 0, (size_t)RR * NN * sizeof(int), stream);
    hipMemsetAsync(cursor, 0, (size_t)RR * NN * sizeof(int), stream);

    // ---- CSR build (shared by both layers) ----
    hist_kernel<<<(RR * EE + 255) / 256, 256, 0, stream>>>(edges, counts);
    scan_kernel<<<RR, 1024, 0, stream>>>(counts, offsets);
    fill_kernel<<<(RR * EE + 255) / 256, 256, 0, stream>>>(edges, offsets, cursor, ssrc);

    const int GGRID = (NN + 3) / 4;

    // ---- layer 1: h1 = sum_r mean_r( feat @ W1[r] + b1[r] ) ----
    for (int r = 0; r < RR; ++r) {
        dim3 g1((NN + 63) / 64, D_H / 64);
        gemm_bias_kernel<D_H, false><<<g1, 256, 0, stream>>>(
            feat, W1 + (size_t)r * D_IN * D_H, b1 + (size_t)r * D_H, wh, NN);
        if (r == 0)
            gather128_kernel<true><<<GGRID, 256, 0, stream>>>(
                wh, ssrc + (size_t)r * EE, offsets + (size_t)r * NN,
                counts + (size_t)r * NN, h1);
        else
            gather128_kernel<false><<<GGRID, 256, 0, stream>>>(
                wh, ssrc + (size_t)r * EE, offsets + (size_t)r * NN,
                counts + (size_t)r * NN, h1);
    }

    // ---- layer 2: out = sum_r mean_r( relu(h1) @ W2[r] + b2[r] ) ----
    for (int r = 0; r < RR; ++r) {
        dim3 g2((NN + 63) / 64, D_OUT / 64);
        gemm_bias_kernel<D_OUT, true><<<g2, 256, 0, stream>>>(
            h1, W2 + (size_t)r * D_H * D_OUT, b2 + (size_t)r * D_OUT, wh, NN);
        if (r == 0)
            gather64_kernel<true><<<GGRID, 256, 0, stream>>>(
                wh, ssrc + (size_t)r * EE, offsets + (size_t)r * NN,
                counts + (size_t)r * NN, out);
        else
            gather64_kernel<false><<<GGRID, 256, 0, stream>>>(
                wh, ssrc + (size_t)r * EE, offsets + (size_t)r * NN,
                counts + (size_t)r * NN, out);
    }
}

// Round 3
// 461.228 us; speedup vs baseline: 2.0571x; 1.4252x over previous
//
#include <hip/hip_runtime.h>

#define NN 50000
#define EE 200000
#define RR 4
#define D_IN 128
#define D_H 128
#define D_OUT 64

#define SC_TOTAL (RR * NN)                                   // 200000
#define SC_BLOCKS ((SC_TOTAL + 1023) / 1024)                 // 196

#define LDA 136   // LDS row stride in ushorts: keeps 16B row alignment; frag reads <=2-way conflict (free)

typedef __attribute__((ext_vector_type(8))) short bf16x8;
typedef __attribute__((ext_vector_type(4))) float f32x4;

__device__ inline unsigned short f2bf(float x) {   // round-to-nearest-even
    unsigned int u = __float_as_uint(x);
    u += 0x7fffu + ((u >> 16) & 1u);
    return (unsigned short)(u >> 16);
}

// ---------------------------------------------------------------------------
// CSR build
__global__ __launch_bounds__(256) void hist_kernel(
    const int* __restrict__ edges, int* __restrict__ counts)
{
    int idx = blockIdx.x * 256 + threadIdx.x;
    if (idx >= RR * EE) return;
    int r = idx / EE;
    int e = idx - r * EE;
    int dst = edges[r * 2 * EE + EE + e];
    atomicAdd(&counts[r * NN + dst], 1);
}

// phase 1: per-block (1024 counts) sums
__global__ __launch_bounds__(256) void scan_p1(
    const int* __restrict__ c, int* __restrict__ bsum)
{
    __shared__ int l[256];
    int t = threadIdx.x;
    int idx = (blockIdx.x * 256 + t) * 4;
    int s = 0;
    if (idx + 3 < SC_TOTAL) { int4 v = *(const int4*)&c[idx]; s = v.x + v.y + v.z + v.w; }
    else { for (int i = idx; i < SC_TOTAL; ++i) s += c[i]; }
    l[t] = s; __syncthreads();
    for (int off = 128; off > 0; off >>= 1) {
        if (t < off) l[t] += l[t + off];
        __syncthreads();
    }
    if (t == 0) bsum[blockIdx.x] = l[0];
}

// phase 2: exclusive scan of block sums (<=256), one block
__global__ __launch_bounds__(256) void scan_p2(
    int* __restrict__ bsum, int* __restrict__ offsets)
{
    __shared__ int l[256];
    int t = threadIdx.x;
    int v = (t < SC_BLOCKS) ? bsum[t] : 0;
    l[t] = v; __syncthreads();
    for (int off = 1; off < 256; off <<= 1) {
        int x = (t >= off) ? l[t - off] : 0;
        __syncthreads();
        l[t] += x;
        __syncthreads();
    }
    if (t < SC_BLOCKS) bsum[t] = (t > 0) ? l[t - 1] : 0;
    if (t == 0) offsets[SC_TOTAL] = RR * EE;   // sentinel
}

// phase 3: local exclusive prefix + block base
__global__ __launch_bounds__(256) void scan_p3(
    const int* __restrict__ c, const int* __restrict__ bsum, int* __restrict__ offsets)
{
    __shared__ int l[256];
    int t = threadIdx.x;
    int idx = (blockIdx.x * 256 + t) * 4;
    int e0 = 0, e1 = 0, e2 = 0, e3 = 0;
    if (idx + 3 < SC_TOTAL) { int4 v = *(const int4*)&c[idx]; e0 = v.x; e1 = v.y; e2 = v.z; e3 = v.w; }
    else {
        if (idx     < SC_TOTAL) e0 = c[idx];
        if (idx + 1 < SC_TOTAL) e1 = c[idx + 1];
        if (idx + 2 < SC_TOTAL) e2 = c[idx + 2];
        if (idx + 3 < SC_TOTAL) e3 = c[idx + 3];
    }
    int s = e0 + e1 + e2 + e3;
    l[t] = s; __syncthreads();
    for (int off = 1; off < 256; off <<= 1) {
        int x = (t >= off) ? l[t - off] : 0;
        __syncthreads();
        l[t] += x;
        __syncthreads();
    }
    int base = bsum[blockIdx.x] + ((t > 0) ? l[t - 1] : 0);
    if (idx     < SC_TOTAL) offsets[idx]     = base;
    if (idx + 1 < SC_TOTAL) offsets[idx + 1] = base + e0;
    if (idx + 2 < SC_TOTAL) offsets[idx + 2] = base + e0 + e1;
    if (idx + 3 < SC_TOTAL) offsets[idx + 3] = base + e0 + e1 + e2;
}

// scatter src indices into dst-sorted flat order (global offsets already include r*EE)
__global__ __launch_bounds__(256) void fill_kernel(
    const int* __restrict__ edges, const int* __restrict__ offsets,
    int* __restrict__ cursor, int* __restrict__ ssrc)
{
    int idx = blockIdx.x * 256 + threadIdx.x;
    if (idx >= RR * EE) return;
    int r = idx / EE;
    int e = idx - r * EE;
    int src = edges[r * 2 * EE + e];
    int dst = edges[r * 2 * EE + EE + e];
    int p = offsets[r * NN + dst] + atomicAdd(&cursor[r * NN + dst], 1);
    ssrc[p] = src;
}

// ---------------------------------------------------------------------------
// bf16 MFMA GEMM: C_bf16[n x LDM] = (relu?)A_f32[n x 128] @ W_f32[128 x LDM] + b
// 64x64 tile, 256 threads = 4 waves; wave w computes rows [w*16, w*16+16).
template<bool RELU, int LDM>
__global__ __launch_bounds__(256) void gemm_mfma_kernel(
    const float* __restrict__ A, const float* __restrict__ W,
    const float* __restrict__ bias, unsigned short* __restrict__ C, int n)
{
    __shared__ unsigned short Al[64 * LDA];   // [row][k] bf16
    __shared__ unsigned short Wl[64 * LDA];   // [n][k]  bf16 (W transposed)
    const int tid  = threadIdx.x;
    const int row0 = blockIdx.x * 64;
    const int c0   = blockIdx.y * 64;

    // stage A tile [64 x 128] fp32 -> bf16, chunks of 8 elements
    #pragma unroll
    for (int it = 0; it < 4; ++it) {
        int chunk = it * 256 + tid;        // 0..1023
        int r = chunk >> 4;                // 0..63
        int k = (chunk & 15) * 8;
        int grow = row0 + r;
        float4 f0 = make_float4(0.f, 0.f, 0.f, 0.f), f1 = f0;
        if (grow < n) {
            f0 = *(const float4*)&A[(size_t)grow * 128 + k];
            f1 = *(const float4*)&A[(size_t)grow * 128 + k + 4];
        }
        if (RELU) {
            f0.x = fmaxf(f0.x, 0.f); f0.y = fmaxf(f0.y, 0.f);
            f0.z = fmaxf(f0.z, 0.f); f0.w = fmaxf(f0.w, 0.f);
            f1.x = fmaxf(f1.x, 0.f); f1.y = fmaxf(f1.y, 0.f);
            f1.z = fmaxf(f1.z, 0.f); f1.w = fmaxf(f1.w, 0.f);
        }
        union { int4 v; unsigned short h[8]; } u;
        u.h[0] = f2bf(f0.x); u.h[1] = f2bf(f0.y); u.h[2] = f2bf(f0.z); u.h[3] = f2bf(f0.w);
        u.h[4] = f2bf(f1.x); u.h[5] = f2bf(f1.y); u.h[6] = f2bf(f1.z); u.h[7] = f2bf(f1.w);
        *(int4*)&Al[r * LDA + k] = u.v;
    }
    // stage W block [128 x 64] fp32 -> transposed bf16 [n][k]
    for (int i = tid; i < 128 * 64; i += 256) {
        int k  = i >> 6;
        int nn = i & 63;
        Wl[nn * LDA + k] = f2bf(W[k * LDM + c0 + nn]);
    }
    __syncthreads();

    const int wv   = tid >> 6;
    const int lane = tid & 63;
    const int m    = lane & 15;    // A row within tile / C col within tile
    const int q    = lane >> 4;

    bf16x8 afr[4];
    #pragma unroll
    for (int ks = 0; ks < 4; ++ks)
        afr[ks] = *(const bf16x8*)&Al[(wv * 16 + m) * LDA + ks * 32 + q * 8];

    #pragma unroll
    for (int nt = 0; nt < 4; ++nt) {
        f32x4 acc = {0.f, 0.f, 0.f, 0.f};
        #pragma unroll
        for (int ks = 0; ks < 4; ++ks) {
            bf16x8 bfr = *(const bf16x8*)&Wl[(nt * 16 + m) * LDA + ks * 32 + q * 8];
            acc = __builtin_amdgcn_mfma_f32_16x16x32_bf16(afr[ks], bfr, acc, 0, 0, 0);
        }
        float bv = bias[c0 + nt * 16 + m];
        #pragma unroll
        for (int rg = 0; rg < 4; ++rg) {
            int grow = row0 + wv * 16 + q * 4 + rg;
            if (grow < n)
                C[(size_t)grow * LDM + c0 + nt * 16 + m] = f2bf(acc[rg] + bv);
        }
    }
}

// ---------------------------------------------------------------------------
// CSR gather-mean over bf16 rows, 128 wide: one 64-lane wave per node.
template<bool FIRST>
__global__ __launch_bounds__(256) void gather128_kernel(
    const unsigned short* __restrict__ wh, const int* __restrict__ ssrc,
    const int* __restrict__ off, float* __restrict__ acc_out)
{
    int node = blockIdx.x * 4 + (threadIdx.x >> 6);
    if (node >= NN) return;
    int lane  = threadIdx.x & 63;
    int start = off[node];
    int end   = off[node + 1];
    float ax = 0.f, ay = 0.f;
    int j = start;
    for (; j + 1 < end; j += 2) {
        int s0 = ssrc[j], s1 = ssrc[j + 1];
        unsigned int v0 = *(const unsigned int*)&wh[(size_t)s0 * 128 + lane * 2];
        unsigned int v1 = *(const unsigned int*)&wh[(size_t)s1 * 128 + lane * 2];
        ax += __uint_as_float(v0 << 16) + __uint_as_float(v1 << 16);
        ay += __uint_as_float(v0 & 0xffff0000u) + __uint_as_float(v1 & 0xffff0000u);
    }
    if (j < end) {
        unsigned int v0 = *(const unsigned int*)&wh[(size_t)ssrc[j] * 128 + lane * 2];
        ax += __uint_as_float(v0 << 16);
        ay += __uint_as_float(v0 & 0xffff0000u);
    }
    float inv = 1.0f / fmaxf((float)(end - start), 1.0f);
    ax *= inv; ay *= inv;
    float2* p = (float2*)&acc_out[(size_t)node * 128 + lane * 2];
    if (FIRST) { *p = make_float2(ax, ay); }
    else { float2 c = *p; c.x += ax; c.y += ay; *p = c; }
}

// 64 wide: one 32-lane half-wave per node, float2 (bf16 pair) per lane.
template<bool FIRST>
__global__ __launch_bounds__(256) void gather64_kernel(
    const unsigned short* __restrict__ wh, const int* __restrict__ ssrc,
    const int* __restrict__ off, float* __restrict__ out)
{
    int node = blockIdx.x * 8 + (threadIdx.x >> 5);
    if (node >= NN) return;
    int lane  = threadIdx.x & 31;
    int start = off[node];
    int end   = off[node + 1];
    float ax = 0.f, ay = 0.f;
    for (int j = start; j < end; ++j) {
        unsigned int v = *(const unsigned int*)&wh[(size_t)ssrc[j] * 64 + lane * 2];
        ax += __uint_as_float(v << 16);
        ay += __uint_as_float(v & 0xffff0000u);
    }
    float inv = 1.0f / fmaxf((float)(end - start), 1.0f);
    ax *= inv; ay *= inv;
    float2* p = (float2*)&out[(size_t)node * 64 + lane * 2];
    if (FIRST) { *p = make_float2(ax, ay); }
    else { float2 c = *p; c.x += ax; c.y += ay; *p = c; }
}

// ---------------------------------------------------------------------------
extern "C" void kernel_launch(void* const* d_in, const int* in_sizes, int n_in,
                              void* d_out, int out_size, void* d_ws, size_t ws_size,
                              hipStream_t stream)
{
    const float* feat  = (const float*)d_in[0];   // [N,128]
    const float* W1    = (const float*)d_in[1];   // [R,128,128]
    const float* b1    = (const float*)d_in[2];   // [R,128]
    const float* W2    = (const float*)d_in[3];   // [R,128,64]
    const float* b2    = (const float*)d_in[4];   // [R,64]
    const int*   edges = (const int*)d_in[5];     // [R,2,E]
    float* out = (float*)d_out;                   // [N,64] fp32

    // workspace (sizes padded so wh lands on a 16B boundary)
    int* counts  = (int*)d_ws;                         // 200000
    int* offsets = counts + SC_TOTAL;                  // 200004 (incl sentinel + pad)
    int* cursor  = offsets + SC_TOTAL + 4;             // 200000
    int* bsum    = cursor + SC_TOTAL;                  // 256
    int* ssrc    = bsum + 256;                         // 800000
    unsigned short* wh = (unsigned short*)(ssrc + (size_t)RR * EE);  // N*128 bf16 (reused N*64 in L2)
    float* h1 = (float*)(wh + (size_t)NN * D_H);       // N*128 fp32 aggregate

    hipMemsetAsync(counts, 0, (size_t)SC_TOTAL * sizeof(int), stream);
    hipMemsetAsync(cursor, 0, (size_t)SC_TOTAL * sizeof(int), stream);

    // ---- CSR build (shared by both layers) ----
    hist_kernel<<<(RR * EE + 255) / 256, 256, 0, stream>>>(edges, counts);
    scan_p1<<<SC_BLOCKS, 256, 0, stream>>>(counts, bsum);
    scan_p2<<<1, 256, 0, stream>>>(bsum, offsets);
    scan_p3<<<SC_BLOCKS, 256, 0, stream>>>(counts, bsum, offsets);
    fill_kernel<<<(RR * EE + 255) / 256, 256, 0, stream>>>(edges, offsets, cursor, ssrc);

    const int G128 = (NN + 3) / 4;
    const int G64  = (NN + 7) / 8;
    const dim3 gg1((NN + 63) / 64, D_H / 64);
    const dim3 gg2((NN + 63) / 64, D_OUT / 64);

    // ---- layer 1: h1 = sum_r mean_r( feat @ W1[r] + b1[r] ) ----
    for (int r = 0; r < RR; ++r) {
        gemm_mfma_kernel<false, D_H><<<gg1, 256, 0, stream>>>(
            feat, W1 + (size_t)r * D_IN * D_H, b1 + (size_t)r * D_H, wh, NN);
        if (r == 0)
            gather128_kernel<true><<<G128, 256, 0, stream>>>(
                wh, ssrc, offsets + (size_t)r * NN, h1);
        else
            gather128_kernel<false><<<G128, 256, 0, stream>>>(
                wh, ssrc, offsets + (size_t)r * NN, h1);
    }

    // ---- layer 2: out = sum_r mean_r( relu(h1) @ W2[r] + b2[r] ) ----
    for (int r = 0; r < RR; ++r) {
        gemm_mfma_kernel<true, D_OUT><<<gg2, 256, 0, stream>>>(
            h1, W2 + (size_t)r * D_H * D_OUT, b2 + (size_t)r * D_OUT, wh, NN);
        if (r == 0)
            gather64_kernel<true><<<G64, 256, 0, stream>>>(
                wh, ssrc, offsets + (size_t)r * NN, out);
        else
            gather64_kernel<false><<<G64, 256, 0, stream>>>(
                wh, ssrc, offsets + (size_t)r * NN, out);
    }
}

// Round 4
// 438.225 us; speedup vs baseline: 2.1650x; 1.0525x over previous
//
#include <hip/hip_runtime.h>

#define NN 50000
#define EE 200000
#define RR 4
#define MCHUNK 25000

#define SC_TOTAL (RR * NN)                                   // 200000
#define SC_BLOCKS ((SC_TOTAL + 1023) / 1024)                 // 196

#define LDA 136   // LDS row stride (ushorts): 16B-aligned rows, frag reads <=2-way conflict (free)

typedef __attribute__((ext_vector_type(8))) short bf16x8;
typedef __attribute__((ext_vector_type(4))) float f32x4;

__device__ inline unsigned short f2bf(float x) {   // round-to-nearest-even
    unsigned int u = __float_as_uint(x);
    u += 0x7fffu + ((u >> 16) & 1u);
    return (unsigned short)(u >> 16);
}

// ---------------------------------------------------------------------------
// CSR build (unchanged from round 3 — verified)
__global__ __launch_bounds__(256) void hist_kernel(
    const int* __restrict__ edges, int* __restrict__ counts)
{
    int idx = blockIdx.x * 256 + threadIdx.x;
    if (idx >= RR * EE) return;
    int r = idx / EE;
    int e = idx - r * EE;
    int dst = edges[r * 2 * EE + EE + e];
    atomicAdd(&counts[r * NN + dst], 1);
}

__global__ __launch_bounds__(256) void scan_p1(
    const int* __restrict__ c, int* __restrict__ bsum)
{
    __shared__ int l[256];
    int t = threadIdx.x;
    int idx = (blockIdx.x * 256 + t) * 4;
    int s = 0;
    if (idx + 3 < SC_TOTAL) { int4 v = *(const int4*)&c[idx]; s = v.x + v.y + v.z + v.w; }
    else { for (int i = idx; i < SC_TOTAL; ++i) s += c[i]; }
    l[t] = s; __syncthreads();
    for (int off = 128; off > 0; off >>= 1) {
        if (t < off) l[t] += l[t + off];
        __syncthreads();
    }
    if (t == 0) bsum[blockIdx.x] = l[0];
}

__global__ __launch_bounds__(256) void scan_p2(
    int* __restrict__ bsum, int* __restrict__ offsets)
{
    __shared__ int l[256];
    int t = threadIdx.x;
    int v = (t < SC_BLOCKS) ? bsum[t] : 0;
    l[t] = v; __syncthreads();
    for (int off = 1; off < 256; off <<= 1) {
        int x = (t >= off) ? l[t - off] : 0;
        __syncthreads();
        l[t] += x;
        __syncthreads();
    }
    if (t < SC_BLOCKS) bsum[t] = (t > 0) ? l[t - 1] : 0;
    if (t == 0) offsets[SC_TOTAL] = RR * EE;   // sentinel
}

__global__ __launch_bounds__(256) void scan_p3(
    const int* __restrict__ c, const int* __restrict__ bsum, int* __restrict__ offsets)
{
    __shared__ int l[256];
    int t = threadIdx.x;
    int idx = (blockIdx.x * 256 + t) * 4;
    int e0 = 0, e1 = 0, e2 = 0, e3 = 0;
    if (idx + 3 < SC_TOTAL) { int4 v = *(const int4*)&c[idx]; e0 = v.x; e1 = v.y; e2 = v.z; e3 = v.w; }
    else {
        if (idx     < SC_TOTAL) e0 = c[idx];
        if (idx + 1 < SC_TOTAL) e1 = c[idx + 1];
        if (idx + 2 < SC_TOTAL) e2 = c[idx + 2];
        if (idx + 3 < SC_TOTAL) e3 = c[idx + 3];
    }
    int s = e0 + e1 + e2 + e3;
    l[t] = s; __syncthreads();
    for (int off = 1; off < 256; off <<= 1) {
        int x = (t >= off) ? l[t - off] : 0;
        __syncthreads();
        l[t] += x;
        __syncthreads();
    }
    int base = bsum[blockIdx.x] + ((t > 0) ? l[t - 1] : 0);
    if (idx     < SC_TOTAL) offsets[idx]     = base;
    if (idx + 1 < SC_TOTAL) offsets[idx + 1] = base + e0;
    if (idx + 2 < SC_TOTAL) offsets[idx + 2] = base + e0 + e1;
    if (idx + 3 < SC_TOTAL) offsets[idx + 3] = base + e0 + e1 + e2;
}

__global__ __launch_bounds__(256) void fill_kernel(
    const int* __restrict__ edges, const int* __restrict__ offsets,
    int* __restrict__ cursor, int* __restrict__ ssrc)
{
    int idx = blockIdx.x * 256 + threadIdx.x;
    if (idx >= RR * EE) return;
    int r = idx / EE;
    int e = idx - r * EE;
    int src = edges[r * 2 * EE + e];
    int dst = edges[r * 2 * EE + EE + e];
    int p = offsets[r * NN + dst] + atomicAdd(&cursor[r * NN + dst], 1);
    ssrc[p] = src;
}

// per-node 4-bit deg>0 mask
__global__ __launch_bounds__(256) void mask_kernel(
    const int* __restrict__ off, unsigned char* __restrict__ mask)
{
    int v = blockIdx.x * 256 + threadIdx.x;
    if (v >= NN) return;
    unsigned m = 0;
    #pragma unroll
    for (int r = 0; r < RR; ++r)
        if (off[r * NN + v + 1] > off[r * NN + v]) m |= (1u << r);
    mask[v] = (unsigned char)m;
}

// ---------------------------------------------------------------------------
// prep: W1T[128][512], W2T[64][512] (bf16, k-fast = transposed concat weights),
// btab1[16][128], btab2[16][64] (bias combos per deg-mask)
__global__ __launch_bounds__(256) void prep_kernel(
    const float* __restrict__ W1, const float* __restrict__ b1,
    const float* __restrict__ W2, const float* __restrict__ b2,
    unsigned short* __restrict__ W1T, unsigned short* __restrict__ W2T,
    float* __restrict__ btab1, float* __restrict__ btab2)
{
    int b = blockIdx.x, t = threadIdx.x;
    if (b < 256) {                       // W1T: 65536 elems
        int i = b * 256 + t;
        int j = i >> 9, kc = i & 511, r = kc >> 7, k = kc & 127;
        W1T[i] = f2bf(W1[r * 16384 + k * 128 + j]);
    } else if (b < 384) {                // W2T: 32768 elems
        int i = (b - 256) * 256 + t;
        int j = i >> 9, kc = i & 511, r = kc >> 7, k = kc & 127;
        W2T[i] = f2bf(W2[r * 8192 + k * 64 + j]);
    } else if (b < 392) {                // btab1: 2048
        int i = (b - 384) * 256 + t;
        int mm = i >> 7, c = i & 127;
        float s = 0.f;
        #pragma unroll
        for (int r = 0; r < RR; ++r) if (mm & (1 << r)) s += b1[r * 128 + c];
        btab1[i] = s;
    } else {                             // btab2: 1024
        int i = (b - 392) * 256 + t;
        int mm = i >> 6, c = i & 63;
        float s = 0.f;
        #pragma unroll
        for (int r = 0; r < RR; ++r) if (mm & (1 << r)) s += b2[r * 64 + c];
        btab2[i] = s;
    }
}

// ---------------------------------------------------------------------------
// layer-1 gather: wave per (node, etype); mean of fp32 feat rows -> bf16 agg chunk
__global__ __launch_bounds__(256) void gather_l1(
    const float* __restrict__ feat, const int* __restrict__ ssrc,
    const int* __restrict__ off, unsigned short* __restrict__ agg,
    int base, int cnt)
{
    int g  = blockIdx.x * 4 + (threadIdx.x >> 6);
    int nl = g >> 2;
    if (nl >= cnt) return;
    int r    = g & 3;
    int node = base + nl;
    int lane = threadIdx.x & 63;
    int s = off[r * NN + node], e = off[r * NN + node + 1];
    float ax = 0.f, ay = 0.f;
    for (int j = s; j < e; ++j) {
        int src = ssrc[j];
        float2 v = *(const float2*)&feat[(size_t)src * 128 + lane * 2];
        ax += v.x; ay += v.y;
    }
    float inv = (e > s) ? 1.0f / (float)(e - s) : 0.f;
    ax *= inv; ay *= inv;
    unsigned u = ((unsigned)f2bf(ay) << 16) | (unsigned)f2bf(ax);
    *(unsigned*)&agg[(size_t)nl * 512 + r * 128 + lane * 2] = u;
}

// layer-2 gather: same over bf16 h1r rows
__global__ __launch_bounds__(256) void gather_l2(
    const unsigned short* __restrict__ h1r, const int* __restrict__ ssrc,
    const int* __restrict__ off, unsigned short* __restrict__ agg,
    int base, int cnt)
{
    int g  = blockIdx.x * 4 + (threadIdx.x >> 6);
    int nl = g >> 2;
    if (nl >= cnt) return;
    int r    = g & 3;
    int node = base + nl;
    int lane = threadIdx.x & 63;
    int s = off[r * NN + node], e = off[r * NN + node + 1];
    float ax = 0.f, ay = 0.f;
    for (int j = s; j < e; ++j) {
        int src = ssrc[j];
        unsigned v = *(const unsigned*)&h1r[(size_t)src * 128 + lane * 2];
        ax += __uint_as_float(v << 16);
        ay += __uint_as_float(v & 0xffff0000u);
    }
    float inv = (e > s) ? 1.0f / (float)(e - s) : 0.f;
    ax *= inv; ay *= inv;
    unsigned u = ((unsigned)f2bf(ay) << 16) | (unsigned)f2bf(ax);
    *(unsigned*)&agg[(size_t)nl * 512 + r * 128 + lane * 2] = u;
}

// ---------------------------------------------------------------------------
// concat GEMM: C[cnt x ON] = A[cnt x 512]_bf16 @ WT^T + btab[mask]; 64 x ON tile.
// RELU_BF16: relu + bf16 store (layer 1, full h1r); else fp32 store (layer 2).
template<int ON, bool RELU_BF16>
__global__ __launch_bounds__(256) void gemm_cat(
    const unsigned short* __restrict__ A, const unsigned short* __restrict__ WT,
    const float* __restrict__ btab, const unsigned char* __restrict__ mask,
    void* __restrict__ Cout, int base, int cnt)
{
    constexpr int NT = ON / 16;
    __shared__ unsigned short Al[64 * LDA];
    __shared__ unsigned short Wl[ON * LDA];
    const int tid  = threadIdx.x;
    const int wv   = tid >> 6;
    const int lane = tid & 63;
    const int m    = lane & 15;
    const int q    = lane >> 4;
    const int row0 = blockIdx.x * 64;

    f32x4 acc[NT];
    #pragma unroll
    for (int nt = 0; nt < NT; ++nt) acc[nt] = (f32x4){0.f, 0.f, 0.f, 0.f};

    for (int ks = 0; ks < 4; ++ks) {
        // stage A chunk [64 x 128] bf16 (vector copies)
        #pragma unroll
        for (int it = 0; it < 4; ++it) {
            int i = it * 256 + tid;
            int rr = i >> 4, ko = i & 15;
            int row = row0 + rr;
            uint4 v = make_uint4(0, 0, 0, 0);
            if (row < cnt) v = *(const uint4*)&A[(size_t)row * 512 + ks * 128 + ko * 8];
            *(uint4*)&Al[rr * LDA + ko * 8] = v;
        }
        // stage W chunk [ON x 128] bf16
        for (int i = tid; i < ON * 16; i += 256) {
            int nr = i >> 4, ko = i & 15;
            *(uint4*)&Wl[nr * LDA + ko * 8] =
                *(const uint4*)&WT[(size_t)nr * 512 + ks * 128 + ko * 8];
        }
        __syncthreads();

        bf16x8 afr[4];
        #pragma unroll
        for (int kq = 0; kq < 4; ++kq)
            afr[kq] = *(const bf16x8*)&Al[(wv * 16 + m) * LDA + kq * 32 + q * 8];
        #pragma unroll
        for (int nt = 0; nt < NT; ++nt) {
            #pragma unroll
            for (int kq = 0; kq < 4; ++kq) {
                bf16x8 bfr = *(const bf16x8*)&Wl[(nt * 16 + m) * LDA + kq * 32 + q * 8];
                acc[nt] = __builtin_amdgcn_mfma_f32_16x16x32_bf16(afr[kq], bfr, acc[nt], 0, 0, 0);
            }
        }
        __syncthreads();
    }

    // epilogue: + bias-combo table, (relu), store
    int rloc[4]; int mk[4];
    #pragma unroll
    for (int rg = 0; rg < 4; ++rg) {
        rloc[rg] = row0 + wv * 16 + q * 4 + rg;
        mk[rg] = (rloc[rg] < cnt) ? (int)mask[base + rloc[rg]] : 0;
    }
    #pragma unroll
    for (int nt = 0; nt < NT; ++nt) {
        int col = nt * 16 + m;
        #pragma unroll
        for (int rg = 0; rg < 4; ++rg) {
            if (rloc[rg] < cnt) {
                size_t gnode = (size_t)(base + rloc[rg]);
                float val = acc[nt][rg] + btab[mk[rg] * ON + col];
                if (RELU_BF16)
                    ((unsigned short*)Cout)[gnode * ON + col] = f2bf(fmaxf(val, 0.f));
                else
                    ((float*)Cout)[gnode * ON + col] = val;
            }
        }
    }
}

// ---------------------------------------------------------------------------
extern "C" void kernel_launch(void* const* d_in, const int* in_sizes, int n_in,
                              void* d_out, int out_size, void* d_ws, size_t ws_size,
                              hipStream_t stream)
{
    const float* feat  = (const float*)d_in[0];   // [N,128]
    const float* W1    = (const float*)d_in[1];   // [R,128,128]
    const float* b1    = (const float*)d_in[2];   // [R,128]
    const float* W2    = (const float*)d_in[3];   // [R,128,64]
    const float* b2    = (const float*)d_in[4];   // [R,64]
    const int*   edges = (const int*)d_in[5];     // [R,2,E]
    float* out = (float*)d_out;                   // [N,64] fp32

    // workspace layout (256B-aligned regions, ~44.3 MB total)
    char* p = (char*)d_ws;
    auto alloc = [&](size_t bytes) { char* q = p; p += (bytes + 255) & ~(size_t)255; return q; };
    int* counts            = (int*)alloc((size_t)SC_TOTAL * 4);
    int* offsets           = (int*)alloc((size_t)(SC_TOTAL + 4) * 4);
    int* cursor            = (int*)alloc((size_t)SC_TOTAL * 4);
    int* bsum              = (int*)alloc(1024);
    int* ssrc              = (int*)alloc((size_t)RR * EE * 4);
    unsigned char* mask    = (unsigned char*)alloc(NN + 64);
    unsigned short* W1T    = (unsigned short*)alloc((size_t)128 * 512 * 2);
    unsigned short* W2T    = (unsigned short*)alloc((size_t)64 * 512 * 2);
    float* btab1           = (float*)alloc((size_t)16 * 128 * 4);
    float* btab2           = (float*)alloc((size_t)16 * 64 * 4);
    unsigned short* h1r    = (unsigned short*)alloc((size_t)NN * 128 * 2);
    unsigned short* agg    = (unsigned short*)alloc((size_t)MCHUNK * 512 * 2);

    hipMemsetAsync(counts, 0, (size_t)SC_TOTAL * 4, stream);
    hipMemsetAsync(cursor, 0, (size_t)SC_TOTAL * 4, stream);

    prep_kernel<<<396, 256, 0, stream>>>(W1, b1, W2, b2, W1T, W2T, btab1, btab2);

    // CSR build (shared by both layers)
    hist_kernel<<<(RR * EE + 255) / 256, 256, 0, stream>>>(edges, counts);
    scan_p1<<<SC_BLOCKS, 256, 0, stream>>>(counts, bsum);
    scan_p2<<<1, 256, 0, stream>>>(bsum, offsets);
    scan_p3<<<SC_BLOCKS, 256, 0, stream>>>(counts, bsum, offsets);
    fill_kernel<<<(RR * EE + 255) / 256, 256, 0, stream>>>(edges, offsets, cursor, ssrc);
    mask_kernel<<<(NN + 255) / 256, 256, 0, stream>>>(offsets, mask);

    const int GG = (MCHUNK + 63) / 64;   // 391

    // layer 1: aggregate feat per (node,etype) -> concat GEMM -> relu -> h1r (bf16)
    for (int c = 0; c < 2; ++c) {
        int base = c * MCHUNK;
        gather_l1<<<MCHUNK, 256, 0, stream>>>(feat, ssrc, offsets, agg, base, MCHUNK);
        gemm_cat<128, true><<<GG, 256, 0, stream>>>(agg, W1T, btab1, mask, h1r, base, MCHUNK);
    }
    // layer 2: aggregate h1r -> concat GEMM -> out (fp32)
    for (int c = 0; c < 2; ++c) {
        int base = c * MCHUNK;
        gather_l2<<<MCHUNK, 256, 0, stream>>>(h1r, ssrc, offsets, agg, base, MCHUNK);
        gemm_cat<64, false><<<GG, 256, 0, stream>>>(agg, W2T, btab2, mask, out, base, MCHUNK);
    }
}

// Round 5
// 410.075 us; speedup vs baseline: 2.3137x; 1.0686x over previous
//
#include <hip/hip_runtime.h>

#define NN 50000
#define EE 200000
#define RR 4

#define SC_TOTAL (RR * NN)                                   // 200000
#define SC_BLOCKS ((SC_TOTAL + 1023) / 1024)                 // 196

#define LDA 136   // LDS row stride (ushorts): 16B-aligned rows, frag reads <=2-way conflict (free)

typedef __attribute__((ext_vector_type(8))) short bf16x8;
typedef __attribute__((ext_vector_type(4))) float f32x4;

__device__ inline unsigned short f2bf(float x) {   // round-to-nearest-even
    unsigned int u = __float_as_uint(x);
    u += 0x7fffu + ((u >> 16) & 1u);
    return (unsigned short)(u >> 16);
}
__device__ inline float bflo(unsigned u) { return __uint_as_float(u << 16); }
__device__ inline float bfhi(unsigned u) { return __uint_as_float(u & 0xffff0000u); }

// ---------------------------------------------------------------------------
// feat fp32 -> bf16 (once; halves gather traffic)
__global__ __launch_bounds__(256) void feat2bf_kernel(
    const float* __restrict__ feat, unsigned short* __restrict__ featb)
{
    int i = (blockIdx.x * 256 + threadIdx.x) * 4;
    if (i >= NN * 128) return;
    float4 v = *(const float4*)&feat[i];
    unsigned lo = (unsigned)f2bf(v.x) | ((unsigned)f2bf(v.y) << 16);
    unsigned hi = (unsigned)f2bf(v.z) | ((unsigned)f2bf(v.w) << 16);
    *(uint2*)&featb[i] = make_uint2(lo, hi);
}

// ---------------------------------------------------------------------------
// CSR build
__global__ __launch_bounds__(256) void hist_kernel(
    const int* __restrict__ edges, int* __restrict__ counts)
{
    int e = blockIdx.x * 256 + threadIdx.x;
    int r = blockIdx.y;
    if (e >= EE) return;
    int dst = edges[r * 2 * EE + EE + e];
    atomicAdd(&counts[r * NN + dst], 1);
}

__global__ __launch_bounds__(256) void scan_p1(
    const int* __restrict__ c, int* __restrict__ bsum)
{
    __shared__ int l[256];
    int t = threadIdx.x;
    int idx = (blockIdx.x * 256 + t) * 4;
    int s = 0;
    if (idx + 3 < SC_TOTAL) { int4 v = *(const int4*)&c[idx]; s = v.x + v.y + v.z + v.w; }
    else { for (int i = idx; i < SC_TOTAL; ++i) s += c[i]; }
    l[t] = s; __syncthreads();
    for (int off = 128; off > 0; off >>= 1) {
        if (t < off) l[t] += l[t + off];
        __syncthreads();
    }
    if (t == 0) bsum[blockIdx.x] = l[0];
}

__global__ __launch_bounds__(256) void scan_p2(
    int* __restrict__ bsum, int* __restrict__ offsets)
{
    __shared__ int l[256];
    int t = threadIdx.x;
    int v = (t < SC_BLOCKS) ? bsum[t] : 0;
    l[t] = v; __syncthreads();
    for (int off = 1; off < 256; off <<= 1) {
        int x = (t >= off) ? l[t - off] : 0;
        __syncthreads();
        l[t] += x;
        __syncthreads();
    }
    if (t < SC_BLOCKS) bsum[t] = (t > 0) ? l[t - 1] : 0;
    if (t == 0) offsets[SC_TOTAL] = RR * EE;   // sentinel
}

// phase 3 also writes cursor copy (used as atomic running positions by fill)
__global__ __launch_bounds__(256) void scan_p3(
    const int* __restrict__ c, const int* __restrict__ bsum,
    int* __restrict__ offsets, int* __restrict__ cur)
{
    __shared__ int l[256];
    int t = threadIdx.x;
    int idx = (blockIdx.x * 256 + t) * 4;
    int e0 = 0, e1 = 0, e2 = 0, e3 = 0;
    if (idx + 3 < SC_TOTAL) { int4 v = *(const int4*)&c[idx]; e0 = v.x; e1 = v.y; e2 = v.z; e3 = v.w; }
    else {
        if (idx     < SC_TOTAL) e0 = c[idx];
        if (idx + 1 < SC_TOTAL) e1 = c[idx + 1];
        if (idx + 2 < SC_TOTAL) e2 = c[idx + 2];
        if (idx + 3 < SC_TOTAL) e3 = c[idx + 3];
    }
    int s = e0 + e1 + e2 + e3;
    l[t] = s; __syncthreads();
    for (int off = 1; off < 256; off <<= 1) {
        int x = (t >= off) ? l[t - off] : 0;
        __syncthreads();
        l[t] += x;
        __syncthreads();
    }
    int base = bsum[blockIdx.x] + ((t > 0) ? l[t - 1] : 0);
    int o0 = base, o1 = base + e0, o2 = base + e0 + e1, o3 = base + e0 + e1 + e2;
    if (idx     < SC_TOTAL) { offsets[idx]     = o0; cur[idx]     = o0; }
    if (idx + 1 < SC_TOTAL) { offsets[idx + 1] = o1; cur[idx + 1] = o1; }
    if (idx + 2 < SC_TOTAL) { offsets[idx + 2] = o2; cur[idx + 2] = o2; }
    if (idx + 3 < SC_TOTAL) { offsets[idx + 3] = o3; cur[idx + 3] = o3; }
}

__global__ __launch_bounds__(256) void fill_kernel(
    const int* __restrict__ edges, int* __restrict__ cur, int* __restrict__ ssrc)
{
    int e = blockIdx.x * 256 + threadIdx.x;
    int r = blockIdx.y;
    if (e >= EE) return;
    int src = edges[r * 2 * EE + e];
    int dst = edges[r * 2 * EE + EE + e];
    int p = atomicAdd(&cur[r * NN + dst], 1);
    ssrc[p] = src;
}

// per-node 4-bit deg>0 mask
__global__ __launch_bounds__(256) void mask_kernel(
    const int* __restrict__ off, unsigned char* __restrict__ mask)
{
    int v = blockIdx.x * 256 + threadIdx.x;
    if (v >= NN) return;
    unsigned m = 0;
    #pragma unroll
    for (int r = 0; r < RR; ++r)
        if (off[r * NN + v + 1] > off[r * NN + v]) m |= (1u << r);
    mask[v] = (unsigned char)m;
}

// ---------------------------------------------------------------------------
// prep: W1T[128][512], W2T[64][512] (bf16 k-fast), btab1[16][128], btab2[16][64]
__global__ __launch_bounds__(256) void prep_kernel(
    const float* __restrict__ W1, const float* __restrict__ b1,
    const float* __restrict__ W2, const float* __restrict__ b2,
    unsigned short* __restrict__ W1T, unsigned short* __restrict__ W2T,
    float* __restrict__ btab1, float* __restrict__ btab2)
{
    int b = blockIdx.x, t = threadIdx.x;
    if (b < 256) {                       // W1T: 65536 elems
        int i = b * 256 + t;
        int j = i >> 9, kc = i & 511, r = kc >> 7, k = kc & 127;
        W1T[i] = f2bf(W1[r * 16384 + k * 128 + j]);
    } else if (b < 384) {                // W2T: 32768 elems
        int i = (b - 256) * 256 + t;
        int j = i >> 9, kc = i & 511, r = kc >> 7, k = kc & 127;
        W2T[i] = f2bf(W2[r * 8192 + k * 64 + j]);
    } else if (b < 392) {                // btab1: 2048
        int i = (b - 384) * 256 + t;
        int mm = i >> 7, c = i & 127;
        float s = 0.f;
        #pragma unroll
        for (int r = 0; r < RR; ++r) if (mm & (1 << r)) s += b1[r * 128 + c];
        btab1[i] = s;
    } else {                             // btab2: 1024
        int i = (b - 392) * 256 + t;
        int mm = i >> 6, c = i & 63;
        float s = 0.f;
        #pragma unroll
        for (int r = 0; r < RR; ++r) if (mm & (1 << r)) s += b2[r * 64 + c];
        btab2[i] = s;
    }
}

// ---------------------------------------------------------------------------
// fused layer: per 64-node block, for each etype r: gather-mean X rows (bf16)
// directly into Al (K-chunk r of the concat GEMM), stage W chunk, MFMA.
// C = [mean_r] @ WT^T + btab[mask];  RELU_BF16: relu+bf16 store, else fp32.
template<int ON, bool RELU_BF16>
__global__ __launch_bounds__(256) void fused_layer(
    const unsigned short* __restrict__ X,      // [N,128] bf16
    const int* __restrict__ ssrc, const int* __restrict__ off,
    const unsigned short* __restrict__ WT,     // [ON,512] bf16 k-fast
    const float* __restrict__ btab, const unsigned char* __restrict__ mask,
    void* __restrict__ Cout)
{
    constexpr int NT = ON / 16;
    __shared__ __align__(16) unsigned short Al[64 * LDA];
    __shared__ __align__(16) unsigned short Wl[ON * LDA];
    const int tid  = threadIdx.x;
    const int wv   = tid >> 6;
    const int lane = tid & 63;
    const int m    = lane & 15;
    const int q    = lane >> 4;
    const int row0 = blockIdx.x * 64;
    const int nodebase = row0 + wv * 16;

    f32x4 acc[NT];
    #pragma unroll
    for (int nt = 0; nt < NT; ++nt) acc[nt] = (f32x4){0.f, 0.f, 0.f, 0.f};

    for (int r = 0; r < RR; ++r) {
        // --- gather-stage A chunk for etype r: wave wv handles 16 nodes ---
        // one vector load gets the 17 offsets this wave needs
        int oidx = nodebase + (lane < 17 ? lane : 16);
        if (oidx > NN) oidx = NN;
        int off_l = off[r * NN + oidx];

        for (int t = 0; t < 16; ++t) {
            int s = __shfl(off_l, t, 64);
            int e = __shfl(off_l, t + 1, 64);
            int d = e - s;
            int dm = d < 64 ? d : 64;
            // coalesced segment-index load + shfl broadcast
            int idxv = (lane < dm) ? ssrc[s + lane] : 0;
            float ax = 0.f, ay = 0.f;
            for (int j = 0; j < dm; j += 4) {
                int i1 = j + 1, i2 = j + 2, i3 = j + 3;
                int s0 = __shfl(idxv, j, 64);
                int s1 = __shfl(idxv, i1 < dm ? i1 : j, 64);
                int s2 = __shfl(idxv, i2 < dm ? i2 : j, 64);
                int s3 = __shfl(idxv, i3 < dm ? i3 : j, 64);
                unsigned u0 = *(const unsigned*)&X[(size_t)s0 * 128 + lane * 2];
                unsigned u1 = *(const unsigned*)&X[(size_t)s1 * 128 + lane * 2];
                unsigned u2 = *(const unsigned*)&X[(size_t)s2 * 128 + lane * 2];
                unsigned u3 = *(const unsigned*)&X[(size_t)s3 * 128 + lane * 2];
                float w1 = (i1 < dm) ? 1.f : 0.f;
                float w2 = (i2 < dm) ? 1.f : 0.f;
                float w3 = (i3 < dm) ? 1.f : 0.f;
                ax += bflo(u0) + w1 * bflo(u1) + w2 * bflo(u2) + w3 * bflo(u3);
                ay += bfhi(u0) + w1 * bfhi(u1) + w2 * bfhi(u2) + w3 * bfhi(u3);
            }
            for (int j = 64; j < d; ++j) {       // rare high-degree tail
                unsigned u = *(const unsigned*)&X[(size_t)ssrc[s + j] * 128 + lane * 2];
                ax += bflo(u); ay += bfhi(u);
            }
            float inv = (d > 0) ? 1.0f / (float)d : 0.f;
            unsigned o = (unsigned)f2bf(ax * inv) | ((unsigned)f2bf(ay * inv) << 16);
            *(unsigned*)&Al[(wv * 16 + t) * LDA + lane * 2] = o;
        }

        // --- stage W chunk r: [ON x 128] ---
        for (int i = tid; i < ON * 16; i += 256) {
            int nr = i >> 4, ko = i & 15;
            *(uint4*)&Wl[nr * LDA + ko * 8] =
                *(const uint4*)&WT[(size_t)nr * 512 + r * 128 + ko * 8];
        }
        __syncthreads();

        bf16x8 afr[4];
        #pragma unroll
        for (int kq = 0; kq < 4; ++kq)
            afr[kq] = *(const bf16x8*)&Al[(wv * 16 + m) * LDA + kq * 32 + q * 8];
        #pragma unroll
        for (int nt = 0; nt < NT; ++nt) {
            #pragma unroll
            for (int kq = 0; kq < 4; ++kq) {
                bf16x8 bfr = *(const bf16x8*)&Wl[(nt * 16 + m) * LDA + kq * 32 + q * 8];
                acc[nt] = __builtin_amdgcn_mfma_f32_16x16x32_bf16(afr[kq], bfr, acc[nt], 0, 0, 0);
            }
        }
        __syncthreads();
    }

    // --- epilogue: + bias-combo, (relu), store ---
    int rloc[4]; int mk[4];
    #pragma unroll
    for (int rg = 0; rg < 4; ++rg) {
        rloc[rg] = row0 + wv * 16 + q * 4 + rg;
        mk[rg] = (rloc[rg] < NN) ? (int)mask[rloc[rg]] : 0;
    }
    #pragma unroll
    for (int nt = 0; nt < NT; ++nt) {
        int col = nt * 16 + m;
        #pragma unroll
        for (int rg = 0; rg < 4; ++rg) {
            if (rloc[rg] < NN) {
                float val = acc[nt][rg] + btab[mk[rg] * ON + col];
                if (RELU_BF16)
                    ((unsigned short*)Cout)[(size_t)rloc[rg] * ON + col] = f2bf(fmaxf(val, 0.f));
                else
                    ((float*)Cout)[(size_t)rloc[rg] * ON + col] = val;
            }
        }
    }
}

// ---------------------------------------------------------------------------
extern "C" void kernel_launch(void* const* d_in, const int* in_sizes, int n_in,
                              void* d_out, int out_size, void* d_ws, size_t ws_size,
                              hipStream_t stream)
{
    const float* feat  = (const float*)d_in[0];   // [N,128]
    const float* W1    = (const float*)d_in[1];   // [R,128,128]
    const float* b1    = (const float*)d_in[2];   // [R,128]
    const float* W2    = (const float*)d_in[3];   // [R,128,64]
    const float* b2    = (const float*)d_in[4];   // [R,64]
    const int*   edges = (const int*)d_in[5];     // [R,2,E]
    float* out = (float*)d_out;                   // [N,64] fp32

    // workspace (~31 MB)
    char* p = (char*)d_ws;
    auto alloc = [&](size_t bytes) { char* q = p; p += (bytes + 255) & ~(size_t)255; return q; };
    int* counts            = (int*)alloc((size_t)SC_TOTAL * 4);
    int* offsets           = (int*)alloc((size_t)(SC_TOTAL + 4) * 4);
    int* cur               = (int*)alloc((size_t)SC_TOTAL * 4);
    int* bsum              = (int*)alloc(1024);
    int* ssrc              = (int*)alloc((size_t)RR * EE * 4);
    unsigned char* mask    = (unsigned char*)alloc(NN + 64);
    unsigned short* W1T    = (unsigned short*)alloc((size_t)128 * 512 * 2);
    unsigned short* W2T    = (unsigned short*)alloc((size_t)64 * 512 * 2);
    float* btab1           = (float*)alloc((size_t)16 * 128 * 4);
    float* btab2           = (float*)alloc((size_t)16 * 64 * 4);
    unsigned short* featb  = (unsigned short*)alloc((size_t)NN * 128 * 2);
    unsigned short* h1r    = (unsigned short*)alloc((size_t)NN * 128 * 2);

    hipMemsetAsync(counts, 0, (size_t)SC_TOTAL * 4, stream);

    feat2bf_kernel<<<(NN * 128 / 4 + 255) / 256, 256, 0, stream>>>(feat, featb);
    prep_kernel<<<396, 256, 0, stream>>>(W1, b1, W2, b2, W1T, W2T, btab1, btab2);

    // CSR build (shared by both layers)
    dim3 eg((EE + 255) / 256, RR);
    hist_kernel<<<eg, 256, 0, stream>>>(edges, counts);
    scan_p1<<<SC_BLOCKS, 256, 0, stream>>>(counts, bsum);
    scan_p2<<<1, 256, 0, stream>>>(bsum, offsets);
    scan_p3<<<SC_BLOCKS, 256, 0, stream>>>(counts, bsum, offsets, cur);
    fill_kernel<<<eg, 256, 0, stream>>>(edges, cur, ssrc);
    mask_kernel<<<(NN + 255) / 256, 256, 0, stream>>>(offsets, mask);

    const int GB = (NN + 63) / 64;   // 782

    // layer 1: fused gather(featb) + concat GEMM + relu -> h1r (bf16)
    fused_layer<128, true><<<GB, 256, 0, stream>>>(
        featb, ssrc, offsets, W1T, btab1, mask, h1r);
    // layer 2: fused gather(h1r) + concat GEMM -> out (fp32)
    fused_layer<64, false><<<GB, 256, 0, stream>>>(
        h1r, ssrc, offsets, W2T, btab2, mask, out);
}

// Round 6
// 330.650 us; speedup vs baseline: 2.8694x; 1.2402x over previous
//
#include <hip/hip_runtime.h>

#define NN 50000
#define EE 200000
#define RR 4
#define MCHUNK 25000

#define SC_TOTAL (RR * NN)                                   // 200000
#define SC_BLOCKS ((SC_TOTAL + 1023) / 1024)                 // 196

#define LDA 136   // LDS row stride (ushorts): 16B-aligned rows, frag reads <=2-way conflict (free)

typedef __attribute__((ext_vector_type(8))) short bf16x8;
typedef __attribute__((ext_vector_type(4))) float f32x4;

__device__ inline unsigned short f2bf(float x) {   // round-to-nearest-even
    unsigned int u = __float_as_uint(x);
    u += 0x7fffu + ((u >> 16) & 1u);
    return (unsigned short)(u >> 16);
}
__device__ inline float bflo(unsigned u) { return __uint_as_float(u << 16); }
__device__ inline float bfhi(unsigned u) { return __uint_as_float(u & 0xffff0000u); }

// ---------------------------------------------------------------------------
// feat fp32 -> bf16 (once; halves gather traffic)
__global__ __launch_bounds__(256) void feat2bf_kernel(
    const float* __restrict__ feat, unsigned short* __restrict__ featb)
{
    int i = (blockIdx.x * 256 + threadIdx.x) * 4;
    if (i >= NN * 128) return;
    float4 v = *(const float4*)&feat[i];
    unsigned lo = (unsigned)f2bf(v.x) | ((unsigned)f2bf(v.y) << 16);
    unsigned hi = (unsigned)f2bf(v.z) | ((unsigned)f2bf(v.w) << 16);
    *(uint2*)&featb[i] = make_uint2(lo, hi);
}

// ---------------------------------------------------------------------------
// CSR build
__global__ __launch_bounds__(256) void hist_kernel(
    const int* __restrict__ edges, int* __restrict__ counts)
{
    int e = blockIdx.x * 256 + threadIdx.x;
    int r = blockIdx.y;
    if (e >= EE) return;
    int dst = edges[r * 2 * EE + EE + e];
    atomicAdd(&counts[r * NN + dst], 1);
}

__global__ __launch_bounds__(256) void scan_p1(
    const int* __restrict__ c, int* __restrict__ bsum)
{
    __shared__ int l[256];
    int t = threadIdx.x;
    int idx = (blockIdx.x * 256 + t) * 4;
    int s = 0;
    if (idx + 3 < SC_TOTAL) { int4 v = *(const int4*)&c[idx]; s = v.x + v.y + v.z + v.w; }
    else { for (int i = idx; i < SC_TOTAL; ++i) s += c[i]; }
    l[t] = s; __syncthreads();
    for (int off = 128; off > 0; off >>= 1) {
        if (t < off) l[t] += l[t + off];
        __syncthreads();
    }
    if (t == 0) bsum[blockIdx.x] = l[0];
}

__global__ __launch_bounds__(256) void scan_p2(
    int* __restrict__ bsum, int* __restrict__ offsets)
{
    __shared__ int l[256];
    int t = threadIdx.x;
    int v = (t < SC_BLOCKS) ? bsum[t] : 0;
    l[t] = v; __syncthreads();
    for (int off = 1; off < 256; off <<= 1) {
        int x = (t >= off) ? l[t - off] : 0;
        __syncthreads();
        l[t] += x;
        __syncthreads();
    }
    if (t < SC_BLOCKS) bsum[t] = (t > 0) ? l[t - 1] : 0;
    if (t == 0) offsets[SC_TOTAL] = RR * EE;   // sentinel
}

// phase 3: offsets + cursor copy. cur may ALIAS counts: each thread reads its
// private c[idx..idx+3] before the barriered scan, writes after — no hazard.
__global__ __launch_bounds__(256) void scan_p3(
    const int* __restrict__ c, const int* __restrict__ bsum,
    int* __restrict__ offsets, int* __restrict__ cur)
{
    __shared__ int l[256];
    int t = threadIdx.x;
    int idx = (blockIdx.x * 256 + t) * 4;
    int e0 = 0, e1 = 0, e2 = 0, e3 = 0;
    if (idx + 3 < SC_TOTAL) { int4 v = *(const int4*)&c[idx]; e0 = v.x; e1 = v.y; e2 = v.z; e3 = v.w; }
    else {
        if (idx     < SC_TOTAL) e0 = c[idx];
        if (idx + 1 < SC_TOTAL) e1 = c[idx + 1];
        if (idx + 2 < SC_TOTAL) e2 = c[idx + 2];
        if (idx + 3 < SC_TOTAL) e3 = c[idx + 3];
    }
    int s = e0 + e1 + e2 + e3;
    l[t] = s; __syncthreads();
    for (int off = 1; off < 256; off <<= 1) {
        int x = (t >= off) ? l[t - off] : 0;
        __syncthreads();
        l[t] += x;
        __syncthreads();
    }
    int base = bsum[blockIdx.x] + ((t > 0) ? l[t - 1] : 0);
    int o0 = base, o1 = base + e0, o2 = base + e0 + e1, o3 = base + e0 + e1 + e2;
    if (idx     < SC_TOTAL) { offsets[idx]     = o0; cur[idx]     = o0; }
    if (idx + 1 < SC_TOTAL) { offsets[idx + 1] = o1; cur[idx + 1] = o1; }
    if (idx + 2 < SC_TOTAL) { offsets[idx + 2] = o2; cur[idx + 2] = o2; }
    if (idx + 3 < SC_TOTAL) { offsets[idx + 3] = o3; cur[idx + 3] = o3; }
}

__global__ __launch_bounds__(256) void fill_kernel(
    const int* __restrict__ edges, int* __restrict__ cur, int* __restrict__ ssrc)
{
    int e = blockIdx.x * 256 + threadIdx.x;
    int r = blockIdx.y;
    if (e >= EE) return;
    int src = edges[r * 2 * EE + e];
    int dst = edges[r * 2 * EE + EE + e];
    int p = atomicAdd(&cur[r * NN + dst], 1);
    ssrc[p] = src;
}

// per-node 4-bit deg>0 mask
__global__ __launch_bounds__(256) void mask_kernel(
    const int* __restrict__ off, unsigned char* __restrict__ mask)
{
    int v = blockIdx.x * 256 + threadIdx.x;
    if (v >= NN) return;
    unsigned m = 0;
    #pragma unroll
    for (int r = 0; r < RR; ++r)
        if (off[r * NN + v + 1] > off[r * NN + v]) m |= (1u << r);
    mask[v] = (unsigned char)m;
}

// ---------------------------------------------------------------------------
// prep: W1T[128][512], W2T[64][512] (bf16 k-fast), btab1[16][128], btab2[16][64]
__global__ __launch_bounds__(256) void prep_kernel(
    const float* __restrict__ W1, const float* __restrict__ b1,
    const float* __restrict__ W2, const float* __restrict__ b2,
    unsigned short* __restrict__ W1T, unsigned short* __restrict__ W2T,
    float* __restrict__ btab1, float* __restrict__ btab2)
{
    int b = blockIdx.x, t = threadIdx.x;
    if (b < 256) {                       // W1T: 65536 elems
        int i = b * 256 + t;
        int j = i >> 9, kc = i & 511, r = kc >> 7, k = kc & 127;
        W1T[i] = f2bf(W1[r * 16384 + k * 128 + j]);
    } else if (b < 384) {                // W2T: 32768 elems
        int i = (b - 256) * 256 + t;
        int j = i >> 9, kc = i & 511, r = kc >> 7, k = kc & 127;
        W2T[i] = f2bf(W2[r * 8192 + k * 64 + j]);
    } else if (b < 392) {                // btab1: 2048
        int i = (b - 384) * 256 + t;
        int mm = i >> 7, c = i & 127;
        float s = 0.f;
        #pragma unroll
        for (int r = 0; r < RR; ++r) if (mm & (1 << r)) s += b1[r * 128 + c];
        btab1[i] = s;
    } else {                             // btab2: 1024
        int i = (b - 392) * 256 + t;
        int mm = i >> 6, c = i & 63;
        float s = 0.f;
        #pragma unroll
        for (int r = 0; r < RR; ++r) if (mm & (1 << r)) s += b2[r * 64 + c];
        btab2[i] = s;
    }
}

// ---------------------------------------------------------------------------
// segment gather-mean: quarter-wave (16 lanes x uint4 = 256B row) per
// (node,etype) segment; 4 independent segment streams per wave.
__global__ __launch_bounds__(256) void gather_seg(
    const unsigned short* __restrict__ X,   // [N,128] bf16
    const int* __restrict__ ssrc, const int* __restrict__ off,
    unsigned short* __restrict__ agg,       // [cnt,512] bf16
    int base, int cnt)
{
    int seg = blockIdx.x * 16 + (threadIdx.x >> 4);
    int nl = seg >> 2;
    if (nl >= cnt) return;
    int r    = seg & 3;
    int node = base + nl;
    int l    = threadIdx.x & 15;
    int s = off[r * NN + node];
    int e = off[r * NN + node + 1];
    float a0 = 0.f, a1 = 0.f, a2 = 0.f, a3 = 0.f, a4 = 0.f, a5 = 0.f, a6 = 0.f, a7 = 0.f;
    int j = s;
    for (; j + 1 < e; j += 2) {
        int s0 = ssrc[j], s1 = ssrc[j + 1];
        uint4 u0 = *(const uint4*)&X[(size_t)s0 * 128 + l * 8];
        uint4 u1 = *(const uint4*)&X[(size_t)s1 * 128 + l * 8];
        a0 += bflo(u0.x) + bflo(u1.x); a1 += bfhi(u0.x) + bfhi(u1.x);
        a2 += bflo(u0.y) + bflo(u1.y); a3 += bfhi(u0.y) + bfhi(u1.y);
        a4 += bflo(u0.z) + bflo(u1.z); a5 += bfhi(u0.z) + bfhi(u1.z);
        a6 += bflo(u0.w) + bflo(u1.w); a7 += bfhi(u0.w) + bfhi(u1.w);
    }
    if (j < e) {
        uint4 u0 = *(const uint4*)&X[(size_t)ssrc[j] * 128 + l * 8];
        a0 += bflo(u0.x); a1 += bfhi(u0.x);
        a2 += bflo(u0.y); a3 += bfhi(u0.y);
        a4 += bflo(u0.z); a5 += bfhi(u0.z);
        a6 += bflo(u0.w); a7 += bfhi(u0.w);
    }
    float inv = (e > s) ? 1.0f / (float)(e - s) : 0.f;
    uint4 o;
    o.x = (unsigned)f2bf(a0 * inv) | ((unsigned)f2bf(a1 * inv) << 16);
    o.y = (unsigned)f2bf(a2 * inv) | ((unsigned)f2bf(a3 * inv) << 16);
    o.z = (unsigned)f2bf(a4 * inv) | ((unsigned)f2bf(a5 * inv) << 16);
    o.w = (unsigned)f2bf(a6 * inv) | ((unsigned)f2bf(a7 * inv) << 16);
    *(uint4*)&agg[(size_t)nl * 512 + r * 128 + l * 8] = o;
}

// ---------------------------------------------------------------------------
// concat GEMM: C[cnt x ON] = A[cnt x 512]_bf16 @ WT^T + btab[mask]; 64 x ON tile.
template<int ON, bool RELU_BF16>
__global__ __launch_bounds__(256) void gemm_cat(
    const unsigned short* __restrict__ A, const unsigned short* __restrict__ WT,
    const float* __restrict__ btab, const unsigned char* __restrict__ mask,
    void* __restrict__ Cout, int base, int cnt)
{
    constexpr int NT = ON / 16;
    __shared__ __align__(16) unsigned short Al[64 * LDA];
    __shared__ __align__(16) unsigned short Wl[ON * LDA];
    const int tid  = threadIdx.x;
    const int wv   = tid >> 6;
    const int lane = tid & 63;
    const int m    = lane & 15;
    const int q    = lane >> 4;
    const int row0 = blockIdx.x * 64;

    f32x4 acc[NT];
    #pragma unroll
    for (int nt = 0; nt < NT; ++nt) acc[nt] = (f32x4){0.f, 0.f, 0.f, 0.f};

    for (int ks = 0; ks < 4; ++ks) {
        #pragma unroll
        for (int it = 0; it < 4; ++it) {
            int i = it * 256 + tid;
            int rr = i >> 4, ko = i & 15;
            int row = row0 + rr;
            uint4 v = make_uint4(0, 0, 0, 0);
            if (row < cnt) v = *(const uint4*)&A[(size_t)row * 512 + ks * 128 + ko * 8];
            *(uint4*)&Al[rr * LDA + ko * 8] = v;
        }
        for (int i = tid; i < ON * 16; i += 256) {
            int nr = i >> 4, ko = i & 15;
            *(uint4*)&Wl[nr * LDA + ko * 8] =
                *(const uint4*)&WT[(size_t)nr * 512 + ks * 128 + ko * 8];
        }
        __syncthreads();

        bf16x8 afr[4];
        #pragma unroll
        for (int kq = 0; kq < 4; ++kq)
            afr[kq] = *(const bf16x8*)&Al[(wv * 16 + m) * LDA + kq * 32 + q * 8];
        #pragma unroll
        for (int nt = 0; nt < NT; ++nt) {
            #pragma unroll
            for (int kq = 0; kq < 4; ++kq) {
                bf16x8 bfr = *(const bf16x8*)&Wl[(nt * 16 + m) * LDA + kq * 32 + q * 8];
                acc[nt] = __builtin_amdgcn_mfma_f32_16x16x32_bf16(afr[kq], bfr, acc[nt], 0, 0, 0);
            }
        }
        __syncthreads();
    }

    int rloc[4]; int mk[4];
    #pragma unroll
    for (int rg = 0; rg < 4; ++rg) {
        rloc[rg] = row0 + wv * 16 + q * 4 + rg;
        mk[rg] = (rloc[rg] < cnt) ? (int)mask[base + rloc[rg]] : 0;
    }
    #pragma unroll
    for (int nt = 0; nt < NT; ++nt) {
        int col = nt * 16 + m;
        #pragma unroll
        for (int rg = 0; rg < 4; ++rg) {
            if (rloc[rg] < cnt) {
                size_t gnode = (size_t)(base + rloc[rg]);
                float val = acc[nt][rg] + btab[mk[rg] * ON + col];
                if (RELU_BF16)
                    ((unsigned short*)Cout)[gnode * ON + col] = f2bf(fmaxf(val, 0.f));
                else
                    ((float*)Cout)[gnode * ON + col] = val;
            }
        }
    }
}

// ---------------------------------------------------------------------------
extern "C" void kernel_launch(void* const* d_in, const int* in_sizes, int n_in,
                              void* d_out, int out_size, void* d_ws, size_t ws_size,
                              hipStream_t stream)
{
    const float* feat  = (const float*)d_in[0];   // [N,128]
    const float* W1    = (const float*)d_in[1];   // [R,128,128]
    const float* b1    = (const float*)d_in[2];   // [R,128]
    const float* W2    = (const float*)d_in[3];   // [R,128,64]
    const float* b2    = (const float*)d_in[4];   // [R,64]
    const int*   edges = (const int*)d_in[5];     // [R,2,E]
    float* out = (float*)d_out;                   // [N,64] fp32

    // workspace (~56.3 MB; cur aliases counts)
    char* p = (char*)d_ws;
    auto alloc = [&](size_t bytes) { char* q = p; p += (bytes + 255) & ~(size_t)255; return q; };
    int* counts            = (int*)alloc((size_t)SC_TOTAL * 4);
    int* offsets           = (int*)alloc((size_t)(SC_TOTAL + 4) * 4);
    int* bsum              = (int*)alloc(1024);
    int* ssrc              = (int*)alloc((size_t)RR * EE * 4);
    unsigned char* mask    = (unsigned char*)alloc(NN + 64);
    unsigned short* W1T    = (unsigned short*)alloc((size_t)128 * 512 * 2);
    unsigned short* W2T    = (unsigned short*)alloc((size_t)64 * 512 * 2);
    float* btab1           = (float*)alloc((size_t)16 * 128 * 4);
    float* btab2           = (float*)alloc((size_t)16 * 64 * 4);
    unsigned short* featb  = (unsigned short*)alloc((size_t)NN * 128 * 2);
    unsigned short* h1r    = (unsigned short*)alloc((size_t)NN * 128 * 2);
    unsigned short* agg    = (unsigned short*)alloc((size_t)MCHUNK * 512 * 2);
    int* cur = counts;   // alias: counts dead after scan_p3 reads them

    hipMemsetAsync(counts, 0, (size_t)SC_TOTAL * 4, stream);

    feat2bf_kernel<<<(NN * 128 / 4 + 255) / 256, 256, 0, stream>>>(feat, featb);
    prep_kernel<<<396, 256, 0, stream>>>(W1, b1, W2, b2, W1T, W2T, btab1, btab2);

    // CSR build (shared by both layers)
    dim3 eg((EE + 255) / 256, RR);
    hist_kernel<<<eg, 256, 0, stream>>>(edges, counts);
    scan_p1<<<SC_BLOCKS, 256, 0, stream>>>(counts, bsum);
    scan_p2<<<1, 256, 0, stream>>>(bsum, offsets);
    scan_p3<<<SC_BLOCKS, 256, 0, stream>>>(counts, bsum, offsets, cur);
    fill_kernel<<<eg, 256, 0, stream>>>(edges, cur, ssrc);
    mask_kernel<<<(NN + 255) / 256, 256, 0, stream>>>(offsets, mask);

    const int SEGB = (MCHUNK * 4 + 15) / 16;   // 6250
    const int GG   = (MCHUNK + 63) / 64;       // 391

    // layer 1: gather(featb) -> agg -> concat GEMM + relu -> h1r (bf16)
    for (int c = 0; c < 2; ++c) {
        int base = c * MCHUNK;
        gather_seg<<<SEGB, 256, 0, stream>>>(featb, ssrc, offsets, agg, base, MCHUNK);
        gemm_cat<128, true><<<GG, 256, 0, stream>>>(agg, W1T, btab1, mask, h1r, base, MCHUNK);
    }
    // layer 2: gather(h1r) -> agg -> concat GEMM -> out (fp32)
    for (int c = 0; c < 2; ++c) {
        int base = c * MCHUNK;
        gather_seg<<<SEGB, 256, 0, stream>>>(h1r, ssrc, offsets, agg, base, MCHUNK);
        gemm_cat<64, false><<<GG, 256, 0, stream>>>(agg, W2T, btab2, mask, out, base, MCHUNK);
    }
}